// Round 10
// baseline (66.613 us; speedup 1.0000x reference)
//
#include <hip/hip_runtime.h>
#include <math.h>

// Problem constants (from reference setup_inputs)
#define B 8
#define S 512
#define G 16
#define DA 1024
#define DM 256
#define WIN 12
#define NCH 32                    // s-chunks per batch for partial max/sum
#define RPC (S / NCH)             // 16 rows per chunk
#define DTOT (DA + DM)            // 1280 pooled dims
#define NW 8                      // waves per block (512 threads)
#define RPW (RPC / NW)            // 2 rows per wave in the sweep
#define NSWEEP (NCH * B)          // 256 sweep blocks (placed first)
#define NWIN (B * (G - 1))        // 120 window blocks
#define NBLK (NSWEEP + NWIN)      // 376 blocks, one dispatch

__inline__ __device__ float4 fmax4(float4 a, float4 b) {
    return make_float4(fmaxf(a.x, b.x), fmaxf(a.y, b.y),
                       fmaxf(a.z, b.z), fmaxf(a.w, b.w));
}
__inline__ __device__ float4 add4(float4 a, float4 b) {
    return make_float4(a.x + b.x, a.y + b.y, a.z + b.z, a.w + b.w);
}
__inline__ __device__ float dot4(float4 a, float4 b) {
    return a.x * b.x + a.y * b.y + a.z * b.z + a.w * b.w;
}

// 8-wave (512-thread) batched block reduce: 4 sums in one LDS round.
__inline__ __device__ float4 blockReduceSum4_8(float4 v, float4* sh) {
    int lane = threadIdx.x & 63, w = threadIdx.x >> 6;
#pragma unroll
    for (int o = 32; o > 0; o >>= 1) {
        v.x += __shfl_xor(v.x, o, 64);
        v.y += __shfl_xor(v.y, o, 64);
        v.z += __shfl_xor(v.z, o, 64);
        v.w += __shfl_xor(v.w, o, 64);
    }
    __syncthreads();
    if (lane == 0) sh[w] = v;
    __syncthreads();
    float4 r = sh[0];
#pragma unroll
    for (int ww = 1; ww < 8; ++ww) {
        r.x += sh[ww].x; r.y += sh[ww].y; r.z += sh[ww].z; r.w += sh[ww].w;
    }
    return r;
}

// ONE dispatch:
//  bid <  NSWEEP: sweep chunk -> pmax/psum partials; last-done block per b
//                 (old % 32 == 31 on cnt[b], start-value independent -> no
//                 counter reset across graph replays) computes the g0 logit.
//  bid >= NSWEEP: window logit g>=1 (independent, raw reads only).
__global__ __launch_bounds__(512) void k_main(
    const float* __restrict__ att, const float* __restrict__ mod,
    const float* __restrict__ Wa, const float* __restrict__ Wm,
    const float* __restrict__ ba, const float* __restrict__ bm,
    const int* __restrict__ gidx, const int* __restrict__ mask,
    float* __restrict__ pmax, float* __restrict__ psum,
    unsigned int* __restrict__ cnt, float* __restrict__ out)
{
    __shared__ float part[NW][DTOT];   // 40 KB, shared by all paths
    __shared__ float4 s4[NW];
    __shared__ int isLast;
    const int bid = blockIdx.x;
    const int t = threadIdx.x, lane = t & 63, w = t >> 6;

    const float4* att4 = (const float4*)att;
    const float4* mod4 = (const float4*)mod;

    if (bid < NSWEEP) {
        // ---------------- sweep chunk ----------------
        const int b = bid >> 5, ch = bid & (NCH - 1);

        float4 amax[4], asum[4];
#pragma unroll
        for (int k = 0; k < 4; ++k) {
            amax[k] = make_float4(-INFINITY, -INFINITY, -INFINITY, -INFINITY);
            asum[k] = make_float4(0.f, 0.f, 0.f, 0.f);
        }
        float4 mmax = make_float4(-INFINITY, -INFINITY, -INFINITY, -INFINITY);
        float4 msum = make_float4(0.f, 0.f, 0.f, 0.f);

        const int row0 = b * S + ch * RPC + w * RPW;
#pragma unroll
        for (int r = 0; r < RPW; ++r) {
            const float4* arow = att4 + (size_t)(row0 + r) * (DA / 4);
#pragma unroll
            for (int k = 0; k < 4; ++k) {
                float4 v = arow[lane + 64 * k];
                amax[k] = fmax4(amax[k], v);
                asum[k] = add4(asum[k], v);
            }
            float4 vm = mod4[(size_t)(row0 + r) * (DM / 4) + lane];
            mmax = fmax4(mmax, vm);
            msum = add4(msum, vm);
        }

        const size_t base = ((size_t)b * NCH + ch) * DTOT;
        float4* pr = (float4*)&part[w][0];

        // Pass 1: maxes.
#pragma unroll
        for (int k = 0; k < 4; ++k) pr[lane + 64 * k] = amax[k];
        ((float4*)&part[w][DA])[lane] = mmax;
        __syncthreads();
        for (int d = t; d < DTOT; d += 512) {
            float mx = part[0][d];
#pragma unroll
            for (int ww = 1; ww < NW; ++ww) mx = fmaxf(mx, part[ww][d]);
            pmax[base + d] = mx;
        }
        __syncthreads();

        // Pass 2: sums.
#pragma unroll
        for (int k = 0; k < 4; ++k) pr[lane + 64 * k] = asum[k];
        ((float4*)&part[w][DA])[lane] = msum;
        __syncthreads();
        for (int d = t; d < DTOT; d += 512) {
            float sm = part[0][d];
#pragma unroll
            for (int ww = 1; ww < NW; ++ww) sm += part[ww][d];
            psum[base + d] = sm;
        }

        // Fan-in: release our partials, detect the last-done block for b.
        __threadfence();
        __syncthreads();
        if (t == 0) {
            unsigned int old = __hip_atomic_fetch_add(
                &cnt[b], 1u, __ATOMIC_ACQ_REL, __HIP_MEMORY_SCOPE_AGENT);
            isLast = ((old & (NCH - 1u)) == NCH - 1u) ? 1 : 0;
        }
        __syncthreads();
        if (!isLast) return;

        // ---------------- g0 finale for batch b (winner block) ----------
        __threadfence();   // acquire: invalidate caches before remote reads

        float cmv = (float)mask[b * S + t];   // S == 512 threads

        // Center-row gather dot for g0.
        const int gi = gidx[b * G];
        float cd = 0.f;
        if (t < 256)
            cd = dot4(att4[(size_t)(b * S + gi) * (DA / 4) + t],
                      ((const float4*)Wa)[t]);
        else if (t < 256 + DM / 4)
            cd = dot4(mod4[(size_t)(b * S + gi) * (DM / 4) + (t - 256)],
                      ((const float4*)Wm)[t - 256]);

        // Fixed-order 32-deep merge (deterministic).
        float gd1 = 0.f, gd2 = 0.f;
        for (int d = t; d < DTOT; d += 512) {
            float mx = -INFINITY, sm = 0.f;
#pragma unroll 8
            for (int c2 = 0; c2 < NCH; ++c2) {
                const size_t o = ((size_t)b * NCH + c2) * DTOT + d;
                mx = fmaxf(mx, pmax[o]);
                sm += psum[o];
            }
            float wg1 = (d < DA) ? Wa[DA + d] : Wm[DM + (d - DA)];
            float wg2 = (d < DA) ? Wa[2 * DA + d] : Wm[2 * DM + (d - DA)];
            gd1 += wg1 * mx;
            gd2 += wg2 * sm;
        }
        float4 r = blockReduceSum4_8(make_float4(gd1, gd2, cd, cmv), s4);
        if (t == 0)
            out[b * G + 0] = r.z + r.x + r.y / r.w + ba[0] + bm[0];
    } else {
        // ---------------- window logit g>=1 ----------------
        const int idx = bid - NSWEEP;
        const int b = idx / (G - 1), g = 1 + idx % (G - 1);
        const int gi = gidx[b * G + g];

        // Center-row gather dot: att[gi]·W0a + mod[gi]·W0m.
        float cd = 0.f;
        if (t < 256)
            cd = dot4(att4[(size_t)(b * S + gi) * (DA / 4) + t],
                      ((const float4*)Wa)[t]);
        else if (t < 256 + DM / 4)
            cd = dot4(mod4[(size_t)(b * S + gi) * (DM / 4) + (t - 256)],
                      ((const float4*)Wm)[t - 256]);

        int lo = gi - WIN; if (lo < 0) lo = 0;
        int hi = gi + WIN; if (hi > S - 1) hi = S - 1;

        // Per-d windowed masked max (clamped at 0 by the reference's x*wmf
        // form; window <= 25 < 512 rows always leaves zeros) and masked sum.
        float4 amax2[4], asum2[4];
#pragma unroll
        for (int k = 0; k < 4; ++k) {
            amax2[k] = make_float4(0.f, 0.f, 0.f, 0.f);
            asum2[k] = make_float4(0.f, 0.f, 0.f, 0.f);
        }
        float4 mmax2 = make_float4(0.f, 0.f, 0.f, 0.f);
        float4 msum2 = make_float4(0.f, 0.f, 0.f, 0.f);
        float cn = 0.f;

        for (int s = lo + w; s <= hi; s += NW) {
            if (mask[b * S + s] > 0) {
                const int row = b * S + s;
                const float4* arow = att4 + (size_t)row * (DA / 4);
#pragma unroll
                for (int k = 0; k < 4; ++k) {
                    float4 v = arow[lane + 64 * k];
                    amax2[k] = fmax4(amax2[k], v);
                    asum2[k] = add4(asum2[k], v);
                }
                float4 vm = mod4[(size_t)row * (DM / 4) + lane];
                mmax2 = fmax4(mmax2, vm);
                msum2 = add4(msum2, vm);
                if (lane == 0) cn += 1.f;
            }
        }

        float4* pr = (float4*)&part[w][0];

        // Pass 1: merge maxes, dot with max-slice weights.
#pragma unroll
        for (int k = 0; k < 4; ++k) pr[lane + 64 * k] = amax2[k];
        ((float4*)&part[w][DA])[lane] = mmax2;
        __syncthreads();
        float wdot1 = 0.f;
        for (int d = t; d < DTOT; d += 512) {
            float mx = part[0][d];
#pragma unroll
            for (int ww = 1; ww < 8; ++ww) mx = fmaxf(mx, part[ww][d]);
            float wgt = (d < DA) ? Wa[DA + d] : Wm[DM + (d - DA)];
            wdot1 += wgt * mx;
        }
        __syncthreads();

        // Pass 2: merge sums, dot with avg-slice weights.
#pragma unroll
        for (int k = 0; k < 4; ++k) pr[lane + 64 * k] = asum2[k];
        ((float4*)&part[w][DA])[lane] = msum2;
        __syncthreads();
        float wdot2 = 0.f;
        for (int d = t; d < DTOT; d += 512) {
            float sm = part[0][d];
#pragma unroll
            for (int ww = 1; ww < 8; ++ww) sm += part[ww][d];
            float wgt = (d < DA) ? Wa[2 * DA + d] : Wm[2 * DM + (d - DA)];
            wdot2 += wgt * sm;
        }

        float4 r = blockReduceSum4_8(make_float4(wdot1, wdot2, cd, cn), s4);
        if (t == 0)
            out[b * G + g] = r.z + r.x + r.y / r.w + ba[0] + bm[0];
    }
}

extern "C" void kernel_launch(void* const* d_in, const int* in_sizes, int n_in,
                              void* d_out, int out_size, void* d_ws, size_t ws_size,
                              hipStream_t stream) {
    const float* att  = (const float*)d_in[0];
    const float* mod  = (const float*)d_in[1];
    const float* Wa   = (const float*)d_in[2];
    const float* ba   = (const float*)d_in[3];
    const float* Wm   = (const float*)d_in[4];
    const float* bm   = (const float*)d_in[5];
    // d_in[6] = q_enc (unused by reference)
    const int* gidx   = (const int*)d_in[7];
    const int* mask   = (const int*)d_in[8];
    // d_in[9] = q_mask (unused by reference)
    float* out = (float*)d_out;

    // Workspace layout (floats). cnt needs NO reset: the winner condition
    // (old % 32 == 31) fires exactly once per 32 increments for any start.
    float* ws   = (float*)d_ws;
    float* pmax = ws;                                   // B*NCH*DTOT
    float* psum = pmax + (size_t)B * NCH * DTOT;        // B*NCH*DTOT
    unsigned int* cnt = (unsigned int*)(psum + (size_t)B * NCH * DTOT);  // B

    k_main<<<NBLK, 512, 0, stream>>>(att, mod, Wa, Wm, ba, bm, gidx, mask,
                                     pmax, psum, cnt, out);
}

// Round 11
// 34.324 us; speedup vs baseline: 1.9407x; 1.9407x over previous
//
#include <hip/hip_runtime.h>
#include <math.h>

// Problem constants (from reference setup_inputs)
#define B 8
#define S 512
#define G 16
#define DA 1024
#define DM 256
#define WIN 12
#define NCH 32                    // s-chunks per batch for partial max
#define RPC (S / NCH)             // 16 rows per chunk
#define DTOT (DA + DM)            // 1280 pooled dims
#define NW 8                      // waves per block (512 threads)
#define RPW (RPC / NW)            // 2 rows per wave in the sweep
#define NSWEEP (NCH * B)          // 256 sweep blocks (placed first)
#define NWIN (B * (G - 1))        // 120 window blocks
#define NBLK (NSWEEP + NWIN)      // 376 blocks in K1

__inline__ __device__ float4 fmax4(float4 a, float4 b) {
    return make_float4(fmaxf(a.x, b.x), fmaxf(a.y, b.y),
                       fmaxf(a.z, b.z), fmaxf(a.w, b.w));
}
__inline__ __device__ float4 add4(float4 a, float4 b) {
    return make_float4(a.x + b.x, a.y + b.y, a.z + b.z, a.w + b.w);
}
__inline__ __device__ float dot4(float4 a, float4 b) {
    return a.x * b.x + a.y * b.y + a.z * b.z + a.w * b.w;
}

// 8-wave (512-thread) batched block reduce: 4 sums in one LDS round.
__inline__ __device__ float4 blockReduceSum4_8(float4 v, float4* sh) {
    int lane = threadIdx.x & 63, w = threadIdx.x >> 6;
#pragma unroll
    for (int o = 32; o > 0; o >>= 1) {
        v.x += __shfl_xor(v.x, o, 64);
        v.y += __shfl_xor(v.y, o, 64);
        v.z += __shfl_xor(v.z, o, 64);
        v.w += __shfl_xor(v.w, o, 64);
    }
    __syncthreads();
    if (lane == 0) sh[w] = v;
    __syncthreads();
    float4 r = sh[0];
#pragma unroll
    for (int ww = 1; ww < 8; ++ww) {
        r.x += sh[ww].x; r.y += sh[ww].y; r.z += sh[ww].z; r.w += sh[ww].w;
    }
    return r;
}

// K1: 376 blocks x 512 threads. No atomics, no fences.
//  bid <  NSWEEP: sweep chunk -> pmax d-partials + per-chunk proj2 SCALAR.
//  bid >= NSWEEP: window logit g>=1 (raw reads only, independent).
__global__ __launch_bounds__(512) void k_main(
    const float* __restrict__ att, const float* __restrict__ mod,
    const float* __restrict__ Wa, const float* __restrict__ Wm,
    const float* __restrict__ ba, const float* __restrict__ bm,
    const int* __restrict__ gidx, const int* __restrict__ mask,
    float* __restrict__ pmax, float* __restrict__ psum2,
    float* __restrict__ out)
{
    __shared__ float part[NW][DTOT];   // 40 KB, shared by both paths
    __shared__ float4 s4[NW];
    __shared__ float sA[NW];
    const int bid = blockIdx.x;
    const int t = threadIdx.x, lane = t & 63, w = t >> 6;

    const float4* att4 = (const float4*)att;
    const float4* mod4 = (const float4*)mod;

    if (bid < NSWEEP) {
        // ---------------- sweep chunk ----------------
        const int b = bid >> 5, ch = bid & (NCH - 1);

        float4 amax[4], asum[4];
#pragma unroll
        for (int k = 0; k < 4; ++k) {
            amax[k] = make_float4(-INFINITY, -INFINITY, -INFINITY, -INFINITY);
            asum[k] = make_float4(0.f, 0.f, 0.f, 0.f);
        }
        float4 mmax = make_float4(-INFINITY, -INFINITY, -INFINITY, -INFINITY);
        float4 msum = make_float4(0.f, 0.f, 0.f, 0.f);

        const int row0 = b * S + ch * RPC + w * RPW;
#pragma unroll
        for (int r = 0; r < RPW; ++r) {
            const float4* arow = att4 + (size_t)(row0 + r) * (DA / 4);
#pragma unroll
            for (int k = 0; k < 4; ++k) {
                float4 v = arow[lane + 64 * k];
                amax[k] = fmax4(amax[k], v);
                asum[k] = add4(asum[k], v);
            }
            float4 vm = mod4[(size_t)(row0 + r) * (DM / 4) + lane];
            mmax = fmax4(mmax, vm);
            msum = add4(msum, vm);
        }

        // proj2 scalar: dot register d-sums with avg-slice weights, in-place.
        const float4* W2a4 = (const float4*)(Wa + 2 * DA);
        const float4* W2m4 = (const float4*)(Wm + 2 * DM);
        float p2 = dot4(msum, W2m4[lane]);
#pragma unroll
        for (int k = 0; k < 4; ++k) p2 += dot4(asum[k], W2a4[lane + 64 * k]);
#pragma unroll
        for (int o = 32; o > 0; o >>= 1) p2 += __shfl_xor(p2, o, 64);
        if (lane == 0) sA[w] = p2;

        // Publish per-wave maxes; merge; write pmax (coalesced).
        float4* pr = (float4*)&part[w][0];
#pragma unroll
        for (int k = 0; k < 4; ++k) pr[lane + 64 * k] = amax[k];
        ((float4*)&part[w][DA])[lane] = mmax;
        __syncthreads();

        const size_t base = ((size_t)b * NCH + ch) * DTOT;
        for (int d = t; d < DTOT; d += 512) {
            float mx = part[0][d];
#pragma unroll
            for (int ww = 1; ww < NW; ++ww) mx = fmaxf(mx, part[ww][d]);
            pmax[base + d] = mx;
        }
        if (t == 0) {
            float s = sA[0];
#pragma unroll
            for (int ww = 1; ww < NW; ++ww) s += sA[ww];
            psum2[b * NCH + ch] = s;
        }
    } else {
        // ---------------- window logit g>=1 ----------------
        const int idx = bid - NSWEEP;
        const int b = idx / (G - 1), g = 1 + idx % (G - 1);
        const int gi = gidx[b * G + g];

        // Center-row gather dot: att[gi]·W0a + mod[gi]·W0m.
        float cd = 0.f;
        if (t < 256)
            cd = dot4(att4[(size_t)(b * S + gi) * (DA / 4) + t],
                      ((const float4*)Wa)[t]);
        else if (t < 256 + DM / 4)
            cd = dot4(mod4[(size_t)(b * S + gi) * (DM / 4) + (t - 256)],
                      ((const float4*)Wm)[t - 256]);

        int lo = gi - WIN; if (lo < 0) lo = 0;
        int hi = gi + WIN; if (hi > S - 1) hi = S - 1;

        // Per-d windowed masked max (clamped at 0 by the reference's x*wmf
        // form; window <= 25 < 512 rows always leaves zeros) and masked sum.
        float4 amax2[4], asum2[4];
#pragma unroll
        for (int k = 0; k < 4; ++k) {
            amax2[k] = make_float4(0.f, 0.f, 0.f, 0.f);
            asum2[k] = make_float4(0.f, 0.f, 0.f, 0.f);
        }
        float4 mmax2 = make_float4(0.f, 0.f, 0.f, 0.f);
        float4 msum2 = make_float4(0.f, 0.f, 0.f, 0.f);
        float cn = 0.f;

        for (int s = lo + w; s <= hi; s += NW) {
            if (mask[b * S + s] > 0) {
                const int row = b * S + s;
                const float4* arow = att4 + (size_t)row * (DA / 4);
#pragma unroll
                for (int k = 0; k < 4; ++k) {
                    float4 v = arow[lane + 64 * k];
                    amax2[k] = fmax4(amax2[k], v);
                    asum2[k] = add4(asum2[k], v);
                }
                float4 vm = mod4[(size_t)row * (DM / 4) + lane];
                mmax2 = fmax4(mmax2, vm);
                msum2 = add4(msum2, vm);
                if (lane == 0) cn += 1.f;
            }
        }

        float4* pr = (float4*)&part[w][0];

        // Pass 1: merge maxes, dot with max-slice weights.
#pragma unroll
        for (int k = 0; k < 4; ++k) pr[lane + 64 * k] = amax2[k];
        ((float4*)&part[w][DA])[lane] = mmax2;
        __syncthreads();
        float wdot1 = 0.f;
        for (int d = t; d < DTOT; d += 512) {
            float mx = part[0][d];
#pragma unroll
            for (int ww = 1; ww < 8; ++ww) mx = fmaxf(mx, part[ww][d]);
            float wgt = (d < DA) ? Wa[DA + d] : Wm[DM + (d - DA)];
            wdot1 += wgt * mx;
        }
        __syncthreads();

        // Pass 2: merge sums, dot with avg-slice weights.
#pragma unroll
        for (int k = 0; k < 4; ++k) pr[lane + 64 * k] = asum2[k];
        ((float4*)&part[w][DA])[lane] = msum2;
        __syncthreads();
        float wdot2 = 0.f;
        for (int d = t; d < DTOT; d += 512) {
            float sm = part[0][d];
#pragma unroll
            for (int ww = 1; ww < 8; ++ww) sm += part[ww][d];
            float wgt = (d < DA) ? Wa[2 * DA + d] : Wm[2 * DM + (d - DA)];
            wdot2 += wgt * sm;
        }

        float4 r = blockReduceSum4_8(make_float4(wdot1, wdot2, cd, cn), s4);
        if (t == 0)
            out[b * G + g] = r.z + r.x + r.y / r.w + ba[0] + bm[0];
    }
}

// K2: 8 blocks, one per batch — g0 logit only.
__global__ __launch_bounds__(512) void k_g0(
    const float* __restrict__ att, const float* __restrict__ mod,
    const float* __restrict__ Wa, const float* __restrict__ Wm,
    const float* __restrict__ ba, const float* __restrict__ bm,
    const int* __restrict__ gidx, const int* __restrict__ mask,
    const float* __restrict__ pmax, const float* __restrict__ psum2,
    float* __restrict__ out)
{
    __shared__ float4 s4[NW];
    const int b = blockIdx.x, t = threadIdx.x;

    const float4* att4 = (const float4*)att;
    const float4* mod4 = (const float4*)mod;

    // Center-row gather dot for g0.
    const int gi = gidx[b * G];
    float cd = 0.f;
    if (t < 256)
        cd = dot4(att4[(size_t)(b * S + gi) * (DA / 4) + t],
                  ((const float4*)Wa)[t]);
    else if (t < 256 + DM / 4)
        cd = dot4(mod4[(size_t)(b * S + gi) * (DM / 4) + (t - 256)],
                  ((const float4*)Wm)[t - 256]);

    // Mask count (S == 512 threads) and psum2 scalar pickup (first 32 threads).
    float cmv = (float)mask[b * S + t];
    float p2s = (t < NCH) ? psum2[b * NCH + t] : 0.f;

    // Fixed-order 32-deep max merge, coalesced; dot with max-slice weights.
    float gd1 = 0.f;
    for (int d = t; d < DTOT; d += 512) {
        float mx = -INFINITY;
#pragma unroll 8
        for (int ch = 0; ch < NCH; ++ch)
            mx = fmaxf(mx, pmax[((size_t)b * NCH + ch) * DTOT + d]);
        float wg1 = (d < DA) ? Wa[DA + d] : Wm[DM + (d - DA)];
        gd1 += wg1 * mx;
    }

    float4 r = blockReduceSum4_8(make_float4(gd1, cd, cmv, p2s), s4);
    if (t == 0)
        out[b * G] = r.y + r.x + r.w / r.z + ba[0] + bm[0];
}

extern "C" void kernel_launch(void* const* d_in, const int* in_sizes, int n_in,
                              void* d_out, int out_size, void* d_ws, size_t ws_size,
                              hipStream_t stream) {
    const float* att  = (const float*)d_in[0];
    const float* mod  = (const float*)d_in[1];
    const float* Wa   = (const float*)d_in[2];
    const float* ba   = (const float*)d_in[3];
    const float* Wm   = (const float*)d_in[4];
    const float* bm   = (const float*)d_in[5];
    // d_in[6] = q_enc (unused by reference)
    const int* gidx   = (const int*)d_in[7];
    const int* mask   = (const int*)d_in[8];
    // d_in[9] = q_mask (unused by reference)
    float* out = (float*)d_out;

    // Workspace layout (floats)
    float* ws    = (float*)d_ws;
    float* pmax  = ws;                                  // B*NCH*DTOT
    float* psum2 = pmax + (size_t)B * NCH * DTOT;       // B*NCH

    k_main<<<NBLK, 512, 0, stream>>>(att, mod, Wa, Wm, ba, bm, gidx, mask,
                                     pmax, psum2, out);
    k_g0<<<B, 512, 0, stream>>>(att, mod, Wa, Wm, ba, bm, gidx, mask,
                                pmax, psum2, out);
}

// Round 12
// 18.280 us; speedup vs baseline: 3.6440x; 1.8777x over previous
//
#include <hip/hip_runtime.h>
#include <math.h>

// Problem constants (from reference setup_inputs)
#define B 8
#define S 512
#define G 16
#define DA 1024
#define DM 256
#define WIN 12
#define DTOT (DA + DM)            // 1280 pooled dims
#define NW 8                      // waves per block (512 threads)
#define NWIN (B * (G - 1))        // 120 window blocks (g>=1)
#define NSL 20                    // 64-wide d-slices (16 att + 4 mod)
#define NSCAN (B * NSL)           // 160 g0 scan blocks
#define NBLK (NWIN + NSCAN + B)   // + 8 center blocks = 288 total

__inline__ __device__ float4 fmax4(float4 a, float4 b) {
    return make_float4(fmaxf(a.x, b.x), fmaxf(a.y, b.y),
                       fmaxf(a.z, b.z), fmaxf(a.w, b.w));
}
__inline__ __device__ float4 add4(float4 a, float4 b) {
    return make_float4(a.x + b.x, a.y + b.y, a.z + b.z, a.w + b.w);
}
__inline__ __device__ float dot4(float4 a, float4 b) {
    return a.x * b.x + a.y * b.y + a.z * b.z + a.w * b.w;
}

// 8-wave (512-thread) batched block reduce: 4 sums in one LDS round.
__inline__ __device__ float4 blockReduceSum4_8(float4 v, float4* sh) {
    int lane = threadIdx.x & 63, w = threadIdx.x >> 6;
#pragma unroll
    for (int o = 32; o > 0; o >>= 1) {
        v.x += __shfl_xor(v.x, o, 64);
        v.y += __shfl_xor(v.y, o, 64);
        v.z += __shfl_xor(v.z, o, 64);
        v.w += __shfl_xor(v.w, o, 64);
    }
    __syncthreads();
    if (lane == 0) sh[w] = v;
    __syncthreads();
    float4 r = sh[0];
#pragma unroll
    for (int ww = 1; ww < 8; ++ww) {
        r.x += sh[ww].x; r.y += sh[ww].y; r.z += sh[ww].z; r.w += sh[ww].w;
    }
    return r;
}

// ONE worker kernel, 288 independent blocks (no partials, no fences):
//  bid < NWIN:            window logit g>=1 -> plain store to out[b,g]
//  bid < NWIN+NSCAN:      g0 d-slice scan  -> atomicAdd into out[b,0]
//  else (8 blocks):       g0 center dot + biases -> atomicAdd into out[b,0]
__global__ __launch_bounds__(512) void k_main(
    const float* __restrict__ att, const float* __restrict__ mod,
    const float* __restrict__ Wa, const float* __restrict__ Wm,
    const float* __restrict__ ba, const float* __restrict__ bm,
    const int* __restrict__ gidx, const int* __restrict__ mask,
    float* __restrict__ out)
{
    __shared__ float part[NW][DTOT];   // 40 KB (windows); scans alias 1 KB
    __shared__ float4 s4[NW];
    const int bid = blockIdx.x;
    const int t = threadIdx.x, lane = t & 63, w = t >> 6;

    const float4* att4 = (const float4*)att;
    const float4* mod4 = (const float4*)mod;

    if (bid < NWIN) {
        // ---------------- window logit g>=1 (verified R9-R11 path) --------
        const int b = bid / (G - 1), g = 1 + bid % (G - 1);
        const int gi = gidx[b * G + g];

        // Center-row gather dot: att[gi]·W0a + mod[gi]·W0m.
        float cd = 0.f;
        if (t < 256)
            cd = dot4(att4[(size_t)(b * S + gi) * (DA / 4) + t],
                      ((const float4*)Wa)[t]);
        else if (t < 256 + DM / 4)
            cd = dot4(mod4[(size_t)(b * S + gi) * (DM / 4) + (t - 256)],
                      ((const float4*)Wm)[t - 256]);

        int lo = gi - WIN; if (lo < 0) lo = 0;
        int hi = gi + WIN; if (hi > S - 1) hi = S - 1;

        // Per-d windowed masked max (clamped at 0 by the reference's x*wmf
        // form; window <= 25 < 512 rows always leaves zeros) and masked sum.
        float4 amax2[4], asum2[4];
#pragma unroll
        for (int k = 0; k < 4; ++k) {
            amax2[k] = make_float4(0.f, 0.f, 0.f, 0.f);
            asum2[k] = make_float4(0.f, 0.f, 0.f, 0.f);
        }
        float4 mmax2 = make_float4(0.f, 0.f, 0.f, 0.f);
        float4 msum2 = make_float4(0.f, 0.f, 0.f, 0.f);
        float cn = 0.f;

        for (int s = lo + w; s <= hi; s += NW) {
            if (mask[b * S + s] > 0) {
                const int row = b * S + s;
                const float4* arow = att4 + (size_t)row * (DA / 4);
#pragma unroll
                for (int k = 0; k < 4; ++k) {
                    float4 v = arow[lane + 64 * k];
                    amax2[k] = fmax4(amax2[k], v);
                    asum2[k] = add4(asum2[k], v);
                }
                float4 vm = mod4[(size_t)row * (DM / 4) + lane];
                mmax2 = fmax4(mmax2, vm);
                msum2 = add4(msum2, vm);
                if (lane == 0) cn += 1.f;
            }
        }

        float4* pr = (float4*)&part[w][0];

        // Pass 1: merge maxes, dot with max-slice weights.
#pragma unroll
        for (int k = 0; k < 4; ++k) pr[lane + 64 * k] = amax2[k];
        ((float4*)&part[w][DA])[lane] = mmax2;
        __syncthreads();
        float wdot1 = 0.f;
        for (int d = t; d < DTOT; d += 512) {
            float mx = part[0][d];
#pragma unroll
            for (int ww = 1; ww < 8; ++ww) mx = fmaxf(mx, part[ww][d]);
            float wgt = (d < DA) ? Wa[DA + d] : Wm[DM + (d - DA)];
            wdot1 += wgt * mx;
        }
        __syncthreads();

        // Pass 2: merge sums, dot with avg-slice weights.
#pragma unroll
        for (int k = 0; k < 4; ++k) pr[lane + 64 * k] = asum2[k];
        ((float4*)&part[w][DA])[lane] = msum2;
        __syncthreads();
        float wdot2 = 0.f;
        for (int d = t; d < DTOT; d += 512) {
            float sm = part[0][d];
#pragma unroll
            for (int ww = 1; ww < 8; ++ww) sm += part[ww][d];
            float wgt = (d < DA) ? Wa[2 * DA + d] : Wm[2 * DM + (d - DA)];
            wdot2 += wgt * sm;
        }

        float4 r = blockReduceSum4_8(make_float4(wdot1, wdot2, cd, cn), s4);
        if (t == 0)
            out[b * G + g] = r.z + r.x + r.y / r.w + ba[0] + bm[0];
    } else if (bid < NWIN + NSCAN) {
        // ---------------- g0 d-slice scan (independent, raw reads) --------
        const int idx = bid - NWIN;
        const int b = idx / NSL, c = idx % NSL;

        // Mask count for this batch (S == 512 threads).
        float cmv = (float)mask[b * S + t];
        float cm = blockReduceSum4_8(make_float4(cmv, 0.f, 0.f, 0.f), s4).x;

        // Wave w scans rows s = w, w+8, ...; lane owns d = c*64+lane.
        // g0 max is UNMASKED (reference: jnp.max(x, axis=1)); sum is over all
        // rows (mask all-ones only affects cm).
        float mx = -INFINITY, sm = 0.f;
        if (c < 16) {
            const float* base = att + (size_t)b * S * DA + c * 64 + lane;
#pragma unroll 4
            for (int s = w; s < S; s += NW) {
                float v = base[(size_t)s * DA];
                mx = fmaxf(mx, v);
                sm += v;
            }
        } else {
            const float* base = mod + (size_t)b * S * DM + (c - 16) * 64 + lane;
#pragma unroll 4
            for (int s = w; s < S; s += NW) {
                float v = base[(size_t)s * DM];
                mx = fmaxf(mx, v);
                sm += v;
            }
        }

        // Cross-wave merge through 1 KB of the part buffer.
        float* pMf = &part[0][0];     // 8*64 floats
        float* pSf = &part[0][512];   // 8*64 floats
        pMf[w * 64 + lane] = mx;
        pSf[w * 64 + lane] = sm;
        __syncthreads();

        float val = 0.f;
        if (t < 64) {
            float m2 = pMf[t], s2 = pSf[t];
#pragma unroll
            for (int ww = 1; ww < NW; ++ww) {
                m2 = fmaxf(m2, pMf[ww * 64 + t]);
                s2 += pSf[ww * 64 + t];
            }
            const int d2 = c * 64 + t;
            float w1 = (d2 < DA) ? Wa[DA + d2] : Wm[DM + (d2 - DA)];
            float w2 = (d2 < DA) ? Wa[2 * DA + d2] : Wm[2 * DM + (d2 - DA)];
            val = w1 * m2 + w2 * (s2 / cm);
#pragma unroll
            for (int o = 32; o > 0; o >>= 1) val += __shfl_xor(val, o, 64);
            if (t == 0) atomicAdd(&out[b * G], val);
        }
    } else {
        // ---------------- g0 center dot + biases --------------------------
        const int b = bid - NWIN - NSCAN;
        const int gi = gidx[b * G];
        float cd = 0.f;
        if (t < 256)
            cd = dot4(att4[(size_t)(b * S + gi) * (DA / 4) + t],
                      ((const float4*)Wa)[t]);
        else if (t < 256 + DM / 4)
            cd = dot4(mod4[(size_t)(b * S + gi) * (DM / 4) + (t - 256)],
                      ((const float4*)Wm)[t - 256]);
        float4 r = blockReduceSum4_8(make_float4(cd, 0.f, 0.f, 0.f), s4);
        if (t == 0) atomicAdd(&out[b * G], r.x + ba[0] + bm[0]);
    }
}

extern "C" void kernel_launch(void* const* d_in, const int* in_sizes, int n_in,
                              void* d_out, int out_size, void* d_ws, size_t ws_size,
                              hipStream_t stream) {
    const float* att  = (const float*)d_in[0];
    const float* mod  = (const float*)d_in[1];
    const float* Wa   = (const float*)d_in[2];
    const float* ba   = (const float*)d_in[3];
    const float* Wm   = (const float*)d_in[4];
    const float* bm   = (const float*)d_in[5];
    // d_in[6] = q_enc (unused by reference)
    const int* gidx   = (const int*)d_in[7];
    const int* mask   = (const int*)d_in[8];
    // d_in[9] = q_mask (unused by reference)
    float* out = (float*)d_out;

    // g0 accumulates via atomicAdd -> out must be zeroed every replay.
    hipMemsetAsync(out, 0, (size_t)out_size * sizeof(float), stream);
    k_main<<<NBLK, 512, 0, stream>>>(att, mod, Wa, Wm, ba, bm, gidx, mask, out);
}